// Round 4
// baseline (303.279 us; speedup 1.0000x reference)
//
#include <hip/hip_runtime.h>
#include <hip/hip_bf16.h>
#include <math.h>

#define TWO_N 8192
#define NR 4096
#define D 256
#define BM 128
#define BN 128
#define BKT 64
#define LDK 72  // padded LDS stride in bf16 elems (144 B): b128-aligned, breaks power-of-2 conflicts

typedef __attribute__((ext_vector_type(8))) short bf16x8;
typedef __attribute__((ext_vector_type(4))) float f32x4;

__device__ inline short f2bf(float x) {
  unsigned u = __builtin_bit_cast(unsigned, x);
  u += 0x7fffu + ((u >> 16) & 1u);  // RNE
  return (short)(u >> 16);
}

__global__ void zero_kernel(double* __restrict__ rowsum) {
  int i = blockIdx.x * blockDim.x + threadIdx.x;
  if (i < NR) rowsum[i] = 0.0;
}

// ap[i] = dot(emb[i], emb[i+NR]); one wave per row.
__global__ void ap_kernel(const float* __restrict__ emb, float* __restrict__ ap) {
  const int lane = threadIdx.x & 63;
  const int wid = threadIdx.x >> 6;
  const int i = blockIdx.x * 4 + wid;
  const float4 a = *reinterpret_cast<const float4*>(emb + (size_t)i * D + lane * 4);
  const float4 b = *reinterpret_cast<const float4*>(emb + (size_t)(i + NR) * D + lane * 4);
  float s = a.x * b.x + a.y * b.y + a.z * b.z + a.w * b.w;
#pragma unroll
  for (int off = 32; off >= 1; off >>= 1) s += __shfl_xor(s, off, 64);
  if (lane == 0) ap[i] = s;
}

// Fused bf16-MFMA GEMM (S = E[0:4096] * E^T) + masked sum of e^(s-ap) in f64.
// e^x computed overflow-free as exp2f(frac) * 2^floor(x*log2e), accumulated f64.
// 128x128 tile, 4 waves in 2x2, each wave 64x64 = 4x4 fragments of 16x16x32.
__global__ __launch_bounds__(256, 2) void fused_mfma(
    const float* __restrict__ emb, const unsigned char* __restrict__ negm,
    const float* __restrict__ ap, double* __restrict__ rowsum) {
  __shared__ short As[BM * LDK];
  __shared__ short Bs[BN * LDK];
  const int t = threadIdx.x;
  const int lane = t & 63;
  const int wid = t >> 6;
  const int wr = wid >> 1;
  const int wc = wid & 1;
  const int bi = blockIdx.y;
  const int bj = blockIdx.x;

  f32x4 acc[4][4] = {};

  const int srow = t >> 2;          // 0..63
  const int schunk = (t & 3) * 16;  // f32 col offset within BKT

  for (int kt = 0; kt < D / BKT; ++kt) {
    const int k0 = kt * BKT;
#pragma unroll
    for (int h = 0; h < 2; ++h) {
      const int r = srow + h * 64;
      {
        const float* g = emb + (size_t)(bi * BM + r) * D + k0 + schunk;
        short tmp[16];
#pragma unroll
        for (int u = 0; u < 4; ++u) {
          float4 v = *reinterpret_cast<const float4*>(g + u * 4);
          tmp[u * 4 + 0] = f2bf(v.x);
          tmp[u * 4 + 1] = f2bf(v.y);
          tmp[u * 4 + 2] = f2bf(v.z);
          tmp[u * 4 + 3] = f2bf(v.w);
        }
#pragma unroll
        for (int u = 0; u < 2; ++u)
          *reinterpret_cast<bf16x8*>(&As[r * LDK + schunk + u * 8]) =
              *reinterpret_cast<bf16x8*>(&tmp[u * 8]);
      }
      {
        const float* g = emb + (size_t)(bj * BN + r) * D + k0 + schunk;
        short tmp[16];
#pragma unroll
        for (int u = 0; u < 4; ++u) {
          float4 v = *reinterpret_cast<const float4*>(g + u * 4);
          tmp[u * 4 + 0] = f2bf(v.x);
          tmp[u * 4 + 1] = f2bf(v.y);
          tmp[u * 4 + 2] = f2bf(v.z);
          tmp[u * 4 + 3] = f2bf(v.w);
        }
#pragma unroll
        for (int u = 0; u < 2; ++u)
          *reinterpret_cast<bf16x8*>(&Bs[r * LDK + schunk + u * 8]) =
              *reinterpret_cast<bf16x8*>(&tmp[u * 8]);
      }
    }
    __syncthreads();
#pragma unroll
    for (int kk = 0; kk < 2; ++kk) {
      bf16x8 af[4], bfr[4];
      const int kof = kk * 32 + (lane >> 4) * 8;
#pragma unroll
      for (int m = 0; m < 4; ++m)
        af[m] = *reinterpret_cast<const bf16x8*>(&As[(wr * 64 + m * 16 + (lane & 15)) * LDK + kof]);
#pragma unroll
      for (int n = 0; n < 4; ++n)
        bfr[n] = *reinterpret_cast<const bf16x8*>(&Bs[(wc * 64 + n * 16 + (lane & 15)) * LDK + kof]);
#pragma unroll
      for (int m = 0; m < 4; ++m)
#pragma unroll
        for (int n = 0; n < 4; ++n)
          acc[m][n] = __builtin_amdgcn_mfma_f32_16x16x32_bf16(af[m], bfr[n], acc[m][n], 0, 0, 0);
    }
    __syncthreads();
  }

  // Epilogue. C/D layout: col = lane&15, row = (lane>>4)*4 + reg (m89-verified).
  const int g = lane >> 4;
  const int cl = lane & 15;
  double rs[4][4] = {};

#pragma unroll
  for (int m = 0; m < 4; ++m) {
    const int rowbase = bi * BM + wr * 64 + m * 16 + g * 4;
    float apv[4];
#pragma unroll
    for (int r2 = 0; r2 < 4; ++r2) apv[r2] = ap[rowbase + r2];
#pragma unroll
    for (int n = 0; n < 4; ++n) {
      const int col = bj * BN + wc * 64 + n * 16 + cl;
#pragma unroll
      for (int r2 = 0; r2 < 4; ++r2) {
        const unsigned char msk = negm[(size_t)(rowbase + r2) * TWO_N + col];
        const float x = acc[m][n][r2] - apv[r2];
        // e^x = exp2f(f) * 2^k, k=floor(x*log2e): |x| <= ~690 so k in [-996,996],
        // exponent field 1023+k in (0,2046) -> never overflows/denormals in f64.
        const float tt = x * 1.44269504088896340736f;
        const float kf = floorf(tt);
        const float mant = exp2f(tt - kf);
        const long long ebits = (long long)(1023 + (int)kf) << 52;
        const double sc = __builtin_bit_cast(double, ebits);
        rs[m][r2] += msk ? (double)mant * sc : 0.0;
      }
    }
  }
#pragma unroll
  for (int m = 0; m < 4; ++m)
#pragma unroll
    for (int r2 = 0; r2 < 4; ++r2) {
      double v = rs[m][r2];
#pragma unroll
      for (int off = 8; off >= 1; off >>= 1) v += __shfl_xor(v, off, 64);
      if (cl == 0) atomicAdd(&rowsum[bi * BM + wr * 64 + m * 16 + g * 4 + r2], v);
    }
}

// j_i = log1p(rowsum_i) in f64 (finite: rowsum <= ~e^440); mean over rows.
__global__ void finalize_kernel(const double* __restrict__ rowsum, float* __restrict__ out) {
  __shared__ double red[4];
  const int t = threadIdx.x;
  double s = 0.0;
  for (int i = t; i < NR; i += 256) s += log1p(rowsum[i]);
#pragma unroll
  for (int off = 32; off >= 1; off >>= 1) s += __shfl_xor(s, off, 64);
  if ((t & 63) == 0) red[t >> 6] = s;
  __syncthreads();
  if (t == 0) out[0] = (float)((red[0] + red[1] + red[2] + red[3]) * (1.0 / NR));
}

extern "C" void kernel_launch(void* const* d_in, const int* in_sizes, int n_in,
                              void* d_out, int out_size, void* d_ws, size_t ws_size,
                              hipStream_t stream) {
  const float* emb = (const float*)d_in[0];
  // d_in[1] (pos_mask) unused by the reference.
  const unsigned char* negm = (const unsigned char*)d_in[2];
  float* out = (float*)d_out;
  float* ap = (float*)d_ws;                  // 4096 f32 (16 KB)
  double* rowsum = (double*)((char*)d_ws + 16384);  // 4096 f64 (32 KB), 8B-aligned

  zero_kernel<<<dim3(NR / 256), dim3(256), 0, stream>>>(rowsum);
  ap_kernel<<<dim3(NR / 4), dim3(256), 0, stream>>>(emb, ap);
  fused_mfma<<<dim3(TWO_N / BN, NR / BM), dim3(256), 0, stream>>>(emb, negm, ap, rowsum);
  finalize_kernel<<<dim3(1), dim3(256), 0, stream>>>(rowsum, out);
}

// Round 5
// 296.879 us; speedup vs baseline: 1.0216x; 1.0216x over previous
//
#include <hip/hip_runtime.h>
#include <math.h>

#define TWO_N 8192
#define NR 4096
#define D 256
#define BM 128
#define BN 128
#define BK 64

typedef __attribute__((ext_vector_type(8))) short bf16x8;
typedef __attribute__((ext_vector_type(4))) float f32x4;

#define AS1V const __attribute__((address_space(1))) void
#define AS3V __attribute__((address_space(3))) void

__device__ inline unsigned short f2bf(float x) {
  unsigned u = __builtin_bit_cast(unsigned, x);
  u += 0x7fffu + ((u >> 16) & 1u);  // RNE
  return (unsigned short)(u >> 16);
}

// One-time f32 -> bf16 conversion of all embeddings (8192x256) into ws.
__global__ void cvt_kernel(const float* __restrict__ emb, unsigned short* __restrict__ ebf) {
  const size_t i = ((size_t)blockIdx.x * 256 + threadIdx.x) * 8;
  const float4 a = *reinterpret_cast<const float4*>(emb + i);
  const float4 b = *reinterpret_cast<const float4*>(emb + i + 4);
  union { unsigned short s[8]; bf16x8 v; } o;
  o.s[0] = f2bf(a.x); o.s[1] = f2bf(a.y); o.s[2] = f2bf(a.z); o.s[3] = f2bf(a.w);
  o.s[4] = f2bf(b.x); o.s[5] = f2bf(b.y); o.s[6] = f2bf(b.z); o.s[7] = f2bf(b.w);
  *reinterpret_cast<bf16x8*>(ebf + i) = o.v;
}

// ap[i] = dot(emb[i], emb[i+NR]) (f32, exact); also zero rowsum[i]. One wave/row.
__global__ void ap_zero_kernel(const float* __restrict__ emb, float* __restrict__ ap,
                               double* __restrict__ rowsum) {
  const int lane = threadIdx.x & 63;
  const int wid = threadIdx.x >> 6;
  const int i = blockIdx.x * 4 + wid;
  const float4 a = *reinterpret_cast<const float4*>(emb + (size_t)i * D + lane * 4);
  const float4 b = *reinterpret_cast<const float4*>(emb + (size_t)(i + NR) * D + lane * 4);
  float s = a.x * b.x + a.y * b.y + a.z * b.z + a.w * b.w;
#pragma unroll
  for (int off = 32; off >= 1; off >>= 1) s += __shfl_xor(s, off, 64);
  if (lane == 0) { ap[i] = s; rowsum[i] = 0.0; }
}

// Fused bf16-MFMA GEMM (S = E[0:4096] * E^T) + masked sum of e^(s-ap) in f64.
// m97 structure: linear LDS [128][64] bf16, global_load_lds width-16 staging,
// 2-barrier K-loop, 4 waves 2x2, 4x4 fragments of 16x16x32 per wave.
__global__ __launch_bounds__(256, 3) void fused_mfma(
    const unsigned short* __restrict__ ebf, const unsigned char* __restrict__ negm,
    const float* __restrict__ ap, double* __restrict__ rowsum) {
  __shared__ unsigned short As[BM * BK];
  __shared__ unsigned short Bs[BN * BK];
  const int t = threadIdx.x;
  const int lane = t & 63;
  const int wid = t >> 6;
  const int wr = wid >> 1;
  const int wc = wid & 1;
  // XCD-aware bijective swizzle: grid 2048 = 8 * 256.
  const int sw = (blockIdx.x & 7) * 256 + (blockIdx.x >> 3);
  const int bi = sw >> 6;  // 0..31 row tile
  const int bj = sw & 63;  // 0..63 col tile

  f32x4 acc[4][4] = {};

  const int srow = lane >> 3;       // 0..7: row within 8-row staging chunk
  const int scol = (lane & 7) * 8;  // bf16 col within BK

  for (int kt = 0; kt < D / BK; ++kt) {
    const int k0 = kt * BK;
#pragma unroll
    for (int q = 0; q < 4; ++q) {
      const int rbase = wid * 32 + q * 8;  // wave-uniform
      const unsigned short* gA = ebf + (size_t)(bi * BM + rbase + srow) * D + k0 + scol;
      const unsigned short* gB = ebf + (size_t)(bj * BN + rbase + srow) * D + k0 + scol;
      __builtin_amdgcn_global_load_lds((AS1V*)gA, (AS3V*)(As + rbase * BK), 16, 0, 0);
      __builtin_amdgcn_global_load_lds((AS1V*)gB, (AS3V*)(Bs + rbase * BK), 16, 0, 0);
    }
    __syncthreads();
#pragma unroll
    for (int kk = 0; kk < 2; ++kk) {
      bf16x8 af[4], bfr[4];
      const int kof = kk * 32 + (lane >> 4) * 8;
#pragma unroll
      for (int m = 0; m < 4; ++m)
        af[m] = *reinterpret_cast<const bf16x8*>(&As[(wr * 64 + m * 16 + (lane & 15)) * BK + kof]);
#pragma unroll
      for (int n = 0; n < 4; ++n)
        bfr[n] = *reinterpret_cast<const bf16x8*>(&Bs[(wc * 64 + n * 16 + (lane & 15)) * BK + kof]);
#pragma unroll
      for (int m = 0; m < 4; ++m)
#pragma unroll
        for (int n = 0; n < 4; ++n)
          acc[m][n] = __builtin_amdgcn_mfma_f32_16x16x32_bf16(af[m], bfr[n], acc[m][n], 0, 0, 0);
    }
    __syncthreads();
  }

  // Epilogue. C/D layout: col = lane&15, row = (lane>>4)*4 + reg (m89-verified).
  // e^x = exp2f(frac) * 2^k accumulated in f64: |x| <= ~700 -> exponent field
  // 1023+k stays in (0,2046), never overflows -> output always finite, non-NaN.
  const int g = lane >> 4;
  const int cl = lane & 15;
  double rs[4][4] = {};

#pragma unroll
  for (int m = 0; m < 4; ++m) {
    const int rowbase = bi * BM + wr * 64 + m * 16 + g * 4;
    float apv[4];
#pragma unroll
    for (int r2 = 0; r2 < 4; ++r2) apv[r2] = ap[rowbase + r2];
#pragma unroll
    for (int n = 0; n < 4; ++n) {
      const int col = bj * BN + wc * 64 + n * 16 + cl;
#pragma unroll
      for (int r2 = 0; r2 < 4; ++r2) {
        const unsigned char msk = negm[(size_t)(rowbase + r2) * TWO_N + col];
        const float x = acc[m][n][r2] - apv[r2];
        const float tt = x * 1.44269504088896340736f;
        const float kf = floorf(tt);
        const float mant = exp2f(tt - kf);
        const long long ebits = (long long)(1023 + (int)kf) << 52;
        const double sc = __builtin_bit_cast(double, ebits);
        rs[m][r2] += msk ? (double)mant * sc : 0.0;
      }
    }
  }
#pragma unroll
  for (int m = 0; m < 4; ++m)
#pragma unroll
    for (int r2 = 0; r2 < 4; ++r2) {
      double v = rs[m][r2];
#pragma unroll
      for (int off = 8; off >= 1; off >>= 1) v += __shfl_xor(v, off, 64);
      if (cl == 0) atomicAdd(&rowsum[bi * BM + wr * 64 + m * 16 + g * 4 + r2], v);
    }
}

// j_i = log1p(rowsum_i) in f64 (finite); mean over rows.
__global__ void finalize_kernel(const double* __restrict__ rowsum, float* __restrict__ out) {
  __shared__ double red[4];
  const int t = threadIdx.x;
  double s = 0.0;
  for (int i = t; i < NR; i += 256) s += log1p(rowsum[i]);
#pragma unroll
  for (int off = 32; off >= 1; off >>= 1) s += __shfl_xor(s, off, 64);
  if ((t & 63) == 0) red[t >> 6] = s;
  __syncthreads();
  if (t == 0) out[0] = (float)((red[0] + red[1] + red[2] + red[3]) * (1.0 / NR));
}

extern "C" void kernel_launch(void* const* d_in, const int* in_sizes, int n_in,
                              void* d_out, int out_size, void* d_ws, size_t ws_size,
                              hipStream_t stream) {
  const float* emb = (const float*)d_in[0];
  // d_in[1] (pos_mask) unused by the reference.
  const unsigned char* negm = (const unsigned char*)d_in[2];
  float* out = (float*)d_out;
  unsigned short* ebf = (unsigned short*)d_ws;                    // 4 MB bf16 embeddings
  float* ap = (float*)((char*)d_ws + (size_t)TWO_N * D * 2);      // 16 KB
  double* rowsum = (double*)((char*)d_ws + (size_t)TWO_N * D * 2 + 16384);  // 32 KB

  cvt_kernel<<<dim3(TWO_N * D / 8 / 256), dim3(256), 0, stream>>>(emb, ebf);
  ap_zero_kernel<<<dim3(NR / 4), dim3(256), 0, stream>>>(emb, ap, rowsum);
  fused_mfma<<<dim3((NR / BM) * (TWO_N / BN)), dim3(256), 0, stream>>>(ebf, negm, ap, rowsum);
  finalize_kernel<<<dim3(1), dim3(256), 0, stream>>>(rowsum, out);
}